// Round 3
// baseline (76.208 us; speedup 1.0000x reference)
//
#include <hip/hip_runtime.h>
#include <hip/hip_bf16.h>

typedef __attribute__((ext_vector_type(8))) short bf16x8;
typedef __attribute__((ext_vector_type(4))) short s16x4;
typedef __attribute__((ext_vector_type(4))) float f32x4;

#define B_ 64
#define T_ 1024
#define N_ 512

// ---- reg-staged slab: 32 k-rows x 128 n-cols fp32 -> bf16 LDS [128 n][32 k]
// thread: n-quad = tid&31 (n = 4*(tid&31)), k-quad = tid>>5 (k = 4*(tid>>5)).
struct Slab { float4 v[4]; };   // v[r] = row k+r, cols n..n+3

__device__ __forceinline__ void slab_load(const float* __restrict__ Xb, int kb,
                                          int pbase, int tid, Slab& s) {
  const int n = (tid & 31) * 4, k = (tid >> 5) * 4;
  const float* base = Xb + (size_t)(kb + k) * N_ + pbase + n;
  #pragma unroll
  for (int r = 0; r < 4; ++r)
    s.v[r] = *(const float4*)(base + (size_t)r * N_);
}

// LDS elem layout: row*32 + chunk*8 + sub; 16B chunk XOR-swizzle:
// global k-chunk cg lands at LDS chunk cg ^ ((row>>1)&3)  (involution).
__device__ __forceinline__ void slab_write(short* lds, int tid, const Slab& s) {
  const int nq = tid & 31, kq = tid >> 5;
  const int cg = kq >> 1, h = kq & 1;
  const float* f = (const float*)&s.v[0];          // f[r*4 + c]
  #pragma unroll
  for (int c = 0; c < 4; ++c) {
    const int row = nq * 4 + c;
    const int cc = cg ^ ((row >> 1) & 3);
    s16x4 pk;
    #pragma unroll
    for (int r = 0; r < 4; ++r)
      pk[r] = __builtin_bit_cast(short, __float2bfloat16(f[r * 4 + c]));
    *(s16x4*)&lds[row * 32 + cc * 8 + h * 4] = pk;  // transpose = reg renaming
  }
}

__device__ __forceinline__ bf16x8 frag(const short* lds, int row, int kc) {
  return *(const bf16x8*)&lds[row * 32 + ((kc ^ ((row >> 1) & 3)) * 8)];
}

// ---- K1: diagonal tiles + stats. 1 block per (panel p, batch b).
__global__ __launch_bounds__(256, 2) void k_diag(
    const float* __restrict__ X, float* __restrict__ amu,
    float* __restrict__ invd, float* __restrict__ out)
{
  __shared__ __align__(16) short lds[2][128 * 32];   // 16 KB dbuf
  __shared__ float sAmu[128], sInvd[128];
  const int p = blockIdx.x, b = blockIdx.y, pbase = p * 128;
  const int tid = threadIdx.x, lane = tid & 63, wave = tid >> 6;
  const int wr = wave >> 1, wc = wave & 1;
  const int fr = lane & 15, kc = lane >> 4;
  const float* Xb = X + (size_t)b * T_ * N_;

  f32x4 acc[4][4] = {};
  f32x4 accR[4] = {};
  const short oneb = (short)0x3F80;                  // bf16 1.0
  const bf16x8 ones = { oneb,oneb,oneb,oneb,oneb,oneb,oneb,oneb };

  #define COMPUTE(BUF)                                                        \
    do {                                                                      \
      bf16x8 af[4], bfv[4];                                                   \
      _Pragma("unroll")                                                       \
      for (int mi = 0; mi < 4; ++mi) af[mi] = frag(BUF, wr*64 + mi*16 + fr, kc); \
      _Pragma("unroll")                                                       \
      for (int ni = 0; ni < 4; ++ni) bfv[ni] = frag(BUF, wc*64 + ni*16 + fr, kc); \
      _Pragma("unroll")                                                       \
      for (int mi = 0; mi < 4; ++mi) {                                        \
        accR[mi] = __builtin_amdgcn_mfma_f32_16x16x32_bf16(af[mi], ones, accR[mi], 0,0,0); \
        _Pragma("unroll")                                                     \
        for (int ni = 0; ni < 4; ++ni)                                        \
          acc[mi][ni] = __builtin_amdgcn_mfma_f32_16x16x32_bf16(af[mi], bfv[ni], acc[mi][ni], 0,0,0); \
      }                                                                       \
    } while (0)

  Slab sA, sB;
  slab_load(Xb, 0,  pbase, tid, sA);
  slab_load(Xb, 32, pbase, tid, sB);
  slab_write(lds[0], tid, sA);
  __syncthreads();
  #pragma unroll 1
  for (int kt = 0; kt < 32; kt += 2) {               // 2-deep prefetch
    if (kt + 2 < 32) slab_load(Xb, (kt + 2) * 32, pbase, tid, sA);
    COMPUTE(lds[0]);
    slab_write(lds[1], tid, sB);                     // slab kt+1 (kt+1<32 always)
    __syncthreads();
    if (kt + 3 < 32) slab_load(Xb, (kt + 3) * 32, pbase, tid, sB);
    COMPUTE(lds[1]);
    if (kt + 2 < 32) slab_write(lds[0], tid, sA);
    __syncthreads();
  }

  // stats: diagonal lanes of waves (0,0),(1,1): fr == kc*4+r
  if ((wave == 0 || wave == 3) && kc == (fr >> 2)) {
    const int r = fr & 3;
    #pragma unroll
    for (int mi = 0; mi < 4; ++mi) {
      const int il = wr * 64 + mi * 16 + fr;
      const float rs  = accR[mi][r];
      const float sii = acc[mi][mi][r];
      const float a  = rs * (1.f / 32.f);            // colsum / sqrt(T)
      const float id = rsqrtf(fmaxf(sii - rs * rs * (1.f / 1024.f), 1e-20f));
      sAmu[il] = a; sInvd[il] = id;
      amu [b * N_ + pbase + il] = a;
      invd[b * N_ + pbase + il] = id;
    }
  }
  __syncthreads();

  const int jl = wc * 64 + fr;
  float aj[4], dj[4];
  #pragma unroll
  for (int ni = 0; ni < 4; ++ni) { aj[ni] = sAmu[jl + ni*16]; dj[ni] = sInvd[jl + ni*16]; }
  #pragma unroll
  for (int mi = 0; mi < 4; ++mi) {
    const int il = wr * 64 + mi * 16 + kc * 4;
    float ai[4], di[4];
    #pragma unroll
    for (int r = 0; r < 4; ++r) { ai[r] = sAmu[il + r]; di[r] = sInvd[il + r]; }
    #pragma unroll
    for (int ni = 0; ni < 4; ++ni) {
      #pragma unroll
      for (int r = 0; r < 4; ++r) {
        float v = (acc[mi][ni][r] - ai[r] * aj[ni]) * (di[r] * dj[ni]);
        v = fminf(fmaxf(v, -1.f), 1.f);
        out[((size_t)b * N_ + pbase + il + r) * N_ + pbase + jl + ni * 16] = v;
      }
    }
  }
  #undef COMPUTE
}

// ---- K2: off-diagonal tiles. 6 per batch, XCD-swizzled by batch.
__global__ __launch_bounds__(256, 2) void k_off(
    const float* __restrict__ X, const float* __restrict__ amu,
    const float* __restrict__ invd, float* __restrict__ out)
{
  __shared__ __align__(16) short ldsA[2][128 * 32];  // 16 KB
  __shared__ __align__(16) short ldsB[2][128 * 32];  // 16 KB
  const int bid = (blockIdx.x & 7) * 48 + (blockIdx.x >> 3);   // 384 = 8 XCD x 48
  const int b = bid / 6, t = bid - b * 6;
  const int ip = (t >= 3) + (t >= 5);
  const int jp = (ip == 0) ? t + 1 : (ip == 1 ? t - 1 : 3);
  const int rowBase = ip * 128, colBase = jp * 128;
  const int tid = threadIdx.x, lane = tid & 63, wave = tid >> 6;
  const int wr = wave >> 1, wc = wave & 1;
  const int fr = lane & 15, kc = lane >> 4;
  const float* Xb = X + (size_t)b * T_ * N_;

  f32x4 acc[4][4] = {};

  Slab a0, b0;
  slab_load(Xb, 0, rowBase, tid, a0);
  slab_load(Xb, 0, colBase, tid, b0);
  slab_write(ldsA[0], tid, a0);
  slab_write(ldsB[0], tid, b0);
  __syncthreads();
  int cur = 0;
  #pragma unroll 1
  for (int kt = 0; kt < 32; ++kt) {
    if (kt < 31) {
      slab_load(Xb, (kt + 1) * 32, rowBase, tid, a0);
      slab_load(Xb, (kt + 1) * 32, colBase, tid, b0);
    }
    bf16x8 af[4], bfv[4];
    #pragma unroll
    for (int mi = 0; mi < 4; ++mi) af[mi] = frag(ldsA[cur], wr*64 + mi*16 + fr, kc);
    #pragma unroll
    for (int ni = 0; ni < 4; ++ni) bfv[ni] = frag(ldsB[cur], wc*64 + ni*16 + fr, kc);
    #pragma unroll
    for (int mi = 0; mi < 4; ++mi)
      #pragma unroll
      for (int ni = 0; ni < 4; ++ni)
        acc[mi][ni] = __builtin_amdgcn_mfma_f32_16x16x32_bf16(af[mi], bfv[ni], acc[mi][ni], 0,0,0);
    if (kt < 31) {
      slab_write(ldsA[cur ^ 1], tid, a0);
      slab_write(ldsB[cur ^ 1], tid, b0);
    }
    __syncthreads();
    cur ^= 1;
  }

  const int jc = colBase + wc * 64 + fr;
  float aj[4], dj[4];
  #pragma unroll
  for (int ni = 0; ni < 4; ++ni) {
    aj[ni] = amu [b * N_ + jc + ni * 16];
    dj[ni] = invd[b * N_ + jc + ni * 16];
  }
  #pragma unroll
  for (int mi = 0; mi < 4; ++mi) {
    const int ibase = rowBase + wr * 64 + mi * 16 + kc * 4;
    float ai[4], di[4];
    #pragma unroll
    for (int r = 0; r < 4; ++r) {
      ai[r] = amu [b * N_ + ibase + r];
      di[r] = invd[b * N_ + ibase + r];
    }
    #pragma unroll
    for (int ni = 0; ni < 4; ++ni) {
      f32x4 g;
      #pragma unroll
      for (int r = 0; r < 4; ++r) {
        float v = (acc[mi][ni][r] - ai[r] * aj[ni]) * (di[r] * dj[ni]);
        g[r] = fminf(fmaxf(v, -1.f), 1.f);
      }
      const int J = jc + ni * 16;
      #pragma unroll
      for (int r = 0; r < 4; ++r)
        out[((size_t)b * N_ + ibase + r) * N_ + J] = g[r];     // tile (ip,jp)
      *(f32x4*)&out[((size_t)b * N_ + J) * N_ + ibase] = g;    // mirror (jp,ip)
    }
  }
}

extern "C" void kernel_launch(void* const* d_in, const int* in_sizes, int n_in,
                              void* d_out, int out_size, void* d_ws, size_t ws_size,
                              hipStream_t stream) {
  const float* X = (const float*)d_in[0];
  // bn_weight / bn_bias provably cancel in the correlation output.
  float* out = (float*)d_out;

  float* amu  = (float*)d_ws;                        // 128 KiB
  float* invd = amu + B_ * N_;                       // 128 KiB

  k_diag<<<dim3(4, B_), 256, 0, stream>>>(X, amu, invd, out);
  k_off<<<dim3(8 * 48), 256, 0, stream>>>(X, amu, invd, out);
}

// Round 4
// 68.236 us; speedup vs baseline: 1.1168x; 1.1168x over previous
//
#include <hip/hip_runtime.h>
#include <hip/hip_bf16.h>

typedef __attribute__((ext_vector_type(8))) short bf16x8;
typedef __attribute__((ext_vector_type(4))) short s16x4;
typedef __attribute__((ext_vector_type(4))) float f32x4;

#define B_ 64
#define T_ 1024
#define N_ 512

#define FENCE() asm volatile("" ::: "memory")
#define VMWAIT(N) asm volatile("s_waitcnt vmcnt(" #N ")" ::: "memory")
#define BAR() __builtin_amdgcn_s_barrier()

__device__ __forceinline__ void async16(const void* g, void* l) {
  __builtin_amdgcn_global_load_lds(
      (const __attribute__((address_space(1))) unsigned int*)g,
      (__attribute__((address_space(3))) unsigned int*)l, 16, 0, 0);
}

__device__ __forceinline__ short f2bf(float f) {
  return __builtin_bit_cast(short, __float2bfloat16(f));   // v_cvt_pk path
}
__device__ __forceinline__ float bf2f(short s) {
  return __builtin_bit_cast(float, ((unsigned)(unsigned short)s) << 16);
}

// K1: per (n-strip of 64, batch): transpose fp32 (T,N) -> bf16 (N,T), plus
// per-column sum / sum-of-squares of the bf16-rounded values.
__global__ __launch_bounds__(256, 4) void k_prep(
    const float* __restrict__ X, short* __restrict__ XbT,
    float* __restrict__ amu, float* __restrict__ invd)
{
  __shared__ __align__(16) short tile[64][68];
  const int b   = blockIdx.y;
  const int n0  = blockIdx.x * 64;
  const int tid = threadIdx.x;
  const int nch = tid & 15;
  const int rg  = tid >> 4;

  float s[4] = {0.f,0.f,0.f,0.f}, q[4] = {0.f,0.f,0.f,0.f};

  for (int tt = 0; tt < 16; ++tt) {
    const int t0 = tt * 64;
    #pragma unroll
    for (int i = 0; i < 4; ++i) {
      const int tr = rg + i * 16;
      const float4 v = *(const float4*)&X[((size_t)b*T_ + t0 + tr)*N_ + n0 + nch*4];
      short bb[4];
      bb[0] = f2bf(v.x); bb[1] = f2bf(v.y); bb[2] = f2bf(v.z); bb[3] = f2bf(v.w);
      #pragma unroll
      for (int c = 0; c < 4; ++c) { float f = bf2f(bb[c]); s[c] += f; q[c] += f*f; }
      s16x4 pk = { bb[0], bb[1], bb[2], bb[3] };
      *(s16x4*)&tile[tr][nch*4] = pk;
    }
    __syncthreads();
    #pragma unroll
    for (int i = 0; i < 4; ++i) {
      const int n = rg + i * 16;
      s16x4 o = { tile[nch*4+0][n], tile[nch*4+1][n],
                  tile[nch*4+2][n], tile[nch*4+3][n] };
      *(s16x4*)&XbT[((size_t)b*N_ + n0 + n)*T_ + t0 + nch*4] = o;
    }
    __syncthreads();
  }

  float* fb = (float*)&tile[0][0];
  #pragma unroll
  for (int c = 0; c < 4; ++c) { fb[tid*8 + c] = s[c]; fb[tid*8 + 4 + c] = q[c]; }
  __syncthreads();
  if (tid < 64) {
    const int qc = tid >> 2, c = tid & 3;
    float cs = 0.f, sq = 0.f;
    #pragma unroll
    for (int g = 0; g < 16; ++g) {
      cs += fb[(g*16 + qc)*8 + c];
      sq += fb[(g*16 + qc)*8 + 4 + c];
    }
    const int n = n0 + qc*4 + c;
    amu[b*N_ + n]  = cs * (1.f/32.f);
    invd[b*N_ + n] = rsqrtf(fmaxf(sq - cs*cs*(1.f/1024.f), 1e-20f));
  }
}

// one K-step of MFMA work: 16x mfma_f32_16x16x32_bf16 from swizzled LDS
__device__ __forceinline__ void compute_step(
    const short* A, const short* Bm, int aoff, int boff, int swz,
    f32x4 (&acc)[4][4])
{
  bf16x8 af[4], bfv[4];
  #pragma unroll
  for (int mi = 0; mi < 4; ++mi) af[mi] = *(const bf16x8*)&A[aoff + mi*512 + swz];
  #pragma unroll
  for (int ni = 0; ni < 4; ++ni) bfv[ni] = *(const bf16x8*)&Bm[boff + ni*512 + swz];
  #pragma unroll
  for (int mi = 0; mi < 4; ++mi)
    #pragma unroll
    for (int ni = 0; ni < 4; ++ni)
      acc[mi][ni] = __builtin_amdgcn_mfma_f32_16x16x32_bf16(
          af[mi], bfv[ni], acc[mi][ni], 0, 0, 0);
}

// 3-buffer counted-vmcnt main loop (T4). L = loads/thread/tile (4 off, 2 diag).
template<bool DIAG>
__device__ __forceinline__ void gram_main(
    const short* __restrict__ Xb,
    size_t ga0, size_t ga1, size_t gb0, size_t gb1,
    short (*ldsA)[4096], short (*ldsB)[4096],
    int tid, int aoff, int boff, int swz, f32x4 (&acc)[4][4])
{
  auto stg = [&](int bi, int kb) {
    char* la = (char*)ldsA[bi];
    async16(Xb + ga0 + kb, la + tid*16);
    async16(Xb + ga1 + kb, la + (tid+256)*16);
    if (!DIAG) {
      char* lb = (char*)ldsB[bi];
      async16(Xb + gb0 + kb, lb + tid*16);
      async16(Xb + gb1 + kb, lb + (tid+256)*16);
    }
  };
  auto cmp = [&](int bi) {
    compute_step(ldsA[bi], DIAG ? ldsA[bi] : ldsB[bi], aoff, boff, swz, acc);
  };

  stg(0, 0); stg(1, 32);                       // tiles 0,1 in flight
  #pragma unroll 1
  for (int it = 0; it < 10; ++it) {            // computes tiles 3it..3it+2
    stg(2, (3*it + 2) * 32);
    if (DIAG) { VMWAIT(4); } else { VMWAIT(8); }   // tile 3it retired
    BAR(); FENCE();
    cmp(0);
    FENCE(); BAR();
    stg(0, (3*it + 3) * 32);
    if (DIAG) { VMWAIT(4); } else { VMWAIT(8); }
    BAR(); FENCE();
    cmp(1);
    FENCE(); BAR();
    stg(1, (3*it + 4) * 32);
    if (DIAG) { VMWAIT(4); } else { VMWAIT(8); }
    BAR(); FENCE();
    cmp(2);
    FENCE(); BAR();
  }
  // tail: tiles 30 (buf0), 31 (buf1); no more stages in flight beyond them
  if (DIAG) { VMWAIT(2); } else { VMWAIT(4); }
  BAR(); FENCE();
  cmp(0);
  FENCE(); BAR();
  VMWAIT(0);
  BAR(); FENCE();
  cmp(1);
}

// K2: per-batch symmetric Gram, 10 upper-tri 128x128 tiles/batch.
__global__ __launch_bounds__(256, 3) void k_gram(
    const short* __restrict__ XbT, const float* __restrict__ amu,
    const float* __restrict__ invd, float* __restrict__ out)
{
  __shared__ __align__(16) short ldsA[3][4096];   // 24 KB
  __shared__ __align__(16) short ldsB[3][4096];   // 24 KB

  const int bid = (blockIdx.x & 7) * 80 + (blockIdx.x >> 3);  // 640 = 8 XCD x 80
  const int b = bid / 10;
  const int t = bid - b * 10;
  const int ip = (t >= 4) + (t >= 7) + (t >= 9);
  const int jp = ip + t - ((ip * (9 - ip)) >> 1);
  const int rowBase = ip * 128, colBase = jp * 128;
  const bool diag = (ip == jp);

  const int tid = threadIdx.x, lane = tid & 63, wave = tid >> 6;
  const int wr = wave >> 1, wc = wave & 1;
  const short* Xb = XbT + (size_t)b * N_ * T_;

  // staging addrs: LDS is linear dest; XOR swizzle applied to global source
  const int r0 = tid >> 2, cl = tid & 3;
  const int cg = cl ^ ((r0 >> 1) & 3);
  const size_t ga0 = (size_t)(rowBase + r0)      * T_ + cg * 8;
  const size_t ga1 = (size_t)(rowBase + r0 + 64) * T_ + cg * 8;
  const size_t gb0 = (size_t)(colBase + r0)      * T_ + cg * 8;
  const size_t gb1 = (size_t)(colBase + r0 + 64) * T_ + cg * 8;

  const int fr = lane & 15, kc = lane >> 4;
  const int swz  = (kc ^ ((fr >> 1) & 3)) * 8;   // fragment-read swizzle
  const int aoff = (wr * 64 + fr) * 32;
  const int boff = (wc * 64 + fr) * 32;

  f32x4 acc[4][4] = {};
  if (diag) gram_main<true >(Xb, ga0, ga1, gb0, gb1, ldsA, ldsB, tid, aoff, boff, swz, acc);
  else      gram_main<false>(Xb, ga0, ga1, gb0, gb1, ldsA, ldsB, tid, aoff, boff, swz, acc);

  // Epilogue. C/D map: col = lane&15, row = (lane>>4)*4 + reg.
  const int jc = colBase + wc * 64 + fr;
  float aj[4], dj[4];
  #pragma unroll
  for (int ni = 0; ni < 4; ++ni) {
    aj[ni] = amu [b*N_ + jc + ni*16];
    dj[ni] = invd[b*N_ + jc + ni*16];
  }
  #pragma unroll
  for (int mi = 0; mi < 4; ++mi) {
    const int ibase = rowBase + wr*64 + mi*16 + kc*4;
    float ai[4], di[4];
    #pragma unroll
    for (int r = 0; r < 4; ++r) {
      ai[r] = amu [b*N_ + ibase + r];
      di[r] = invd[b*N_ + ibase + r];
    }
    #pragma unroll
    for (int ni = 0; ni < 4; ++ni) {
      f32x4 g;
      #pragma unroll
      for (int r = 0; r < 4; ++r) {
        float v = (acc[mi][ni][r] - ai[r]*aj[ni]) * (di[r]*dj[ni]);
        g[r] = fminf(fmaxf(v, -1.f), 1.f);
      }
      const int J = jc + ni * 16;
      #pragma unroll
      for (int r = 0; r < 4; ++r)
        out[((size_t)b*N_ + ibase + r)*N_ + J] = g[r];       // tile (ip,jp)
      if (!diag)
        *(f32x4*)&out[((size_t)b*N_ + J)*N_ + ibase] = g;    // mirror (jp,ip)
    }
  }
}

extern "C" void kernel_launch(void* const* d_in, const int* in_sizes, int n_in,
                              void* d_out, int out_size, void* d_ws, size_t ws_size,
                              hipStream_t stream) {
  const float* X = (const float*)d_in[0];
  // bn_weight / bn_bias provably cancel in the correlation output.
  float* out = (float*)d_out;

  char* ws = (char*)d_ws;
  short* XbT  = (short*)ws;                      // 64 MiB bf16 (N,T)
  size_t off  = (size_t)B_ * N_ * T_ * sizeof(short);
  float* amu  = (float*)(ws + off);              // 128 KiB
  float* invd = amu + B_ * N_;                   // 128 KiB

  k_prep<<<dim3(N_/64, B_), 256, 0, stream>>>(X, XbT, amu, invd);
  k_gram<<<dim3(64 * 10), 256, 0, stream>>>(XbT, amu, invd, out);
}